// Round 2
// baseline (342.306 us; speedup 1.0000x reference)
//
#include <hip/hip_runtime.h>
#include <hip/hip_bf16.h>

// LSTM cell: B=16384, D=H=1024. out = (h_next, c_next) fp32, each 16384x1024.
// bf16-MFMA fused 4-gate GEMM, 8-phase-style counted-vmcnt schedule (T3+T4+T5+T1+T2).

#define MROWS 16384
#define NCOLS 1024
#define KTOT  2048

typedef __attribute__((ext_vector_type(8))) short bf16x8;
typedef __attribute__((ext_vector_type(4))) float f32x4;
typedef unsigned int u32;
typedef unsigned short u16;

__device__ __forceinline__ u16 f2bf(float f) {
  union { float f; u32 u; } v; v.f = f;
  u32 r = v.u + 0x7fffu + ((v.u >> 16) & 1u);   // RNE truncate f32->bf16
  return (u16)(r >> 16);
}

__device__ __forceinline__ bf16x8 pack8(float4 lo, float4 hi) {
  bf16x8 v;
  v[0] = (short)f2bf(lo.x); v[1] = (short)f2bf(lo.y);
  v[2] = (short)f2bf(lo.z); v[3] = (short)f2bf(lo.w);
  v[4] = (short)f2bf(hi.x); v[5] = (short)f2bf(hi.y);
  v[6] = (short)f2bf(hi.z); v[7] = (short)f2bf(hi.w);
  return v;
}

__device__ __forceinline__ float tanh_fast(float x) {
  float e = __expf(2.0f * x);
  return 1.0f - 2.0f / (e + 1.0f);
}

typedef __attribute__((address_space(1))) const u32 gas_u32;
typedef __attribute__((address_space(3))) u32 las_u32;

__device__ __forceinline__ void gl_lds16(const void* g, void* l) {
  __builtin_amdgcn_global_load_lds((gas_u32*)g, (las_u32*)l, 16, 0, 0);
}

// ---- conversion kernels ----
__global__ void __launch_bounds__(256) convA(const float* __restrict__ x,
                                             const float* __restrict__ h,
                                             u16* __restrict__ A) {
  u32 t = blockIdx.x * 256u + threadIdx.x;
  #pragma unroll
  for (int i = 0; i < 4; ++i) {
    u32 chunk = t + (u32)i * 1048576u;
    u32 row = chunk >> 8;
    u32 cpos = (chunk & 255u) * 8u;
    const float* src = (cpos < 1024u) ? (x + (size_t)row * 1024 + cpos)
                                      : (h + (size_t)row * 1024 + (cpos - 1024u));
    float4 lo = *(const float4*)src;
    float4 hi = *(const float4*)(src + 4);
    *(bf16x8*)(A + (size_t)chunk * 8) = pack8(lo, hi);
  }
}

__global__ void __launch_bounds__(256) convW(const float* __restrict__ wix, const float* __restrict__ wfx,
                                             const float* __restrict__ wcx, const float* __restrict__ wox,
                                             const float* __restrict__ wih, const float* __restrict__ wfh,
                                             const float* __restrict__ wch, const float* __restrict__ woh,
                                             u16* __restrict__ W) {
  u32 t = blockIdx.x * 256u + threadIdx.x;
  const float* WX[4] = {wix, wfx, wcx, wox};
  const float* WH[4] = {wih, wfh, wch, woh};
  #pragma unroll
  for (int g = 0; g < 4; ++g) {
    u32 c3 = t;
    u32 n = c3 >> 8;
    u32 cpos = (c3 & 255u) * 8u;
    const float* src = (cpos < 1024u) ? (WX[g] + (size_t)n * 1024 + cpos)
                                      : (WH[g] + (size_t)n * 1024 + (cpos - 1024u));
    float4 lo = *(const float4*)src;
    float4 hi = *(const float4*)(src + 4);
    *(bf16x8*)(W + (size_t)g * 2097152 + (size_t)c3 * 8) = pack8(lo, hi);
  }
}

// ---- 8-phase-style fused GEMM ----
// Block: 512 thr = 8 waves (wr 0-1 M-halves x wc 0-3 N-colblocks).
// Tile: 256(M) x [4 gates x 64](N), BK=64, 32 K-tiles.
// B fused rows: fr in [0,256): fi=fr>>4, colblock=fi>>2(==wc), gate=fi&3, col=fr&15.
// LDS: sA[2 dbuf][256][64], sB same = 128 KB. XOR swizzle chunk^=(row&7).
#define SBAR() __builtin_amdgcn_sched_barrier(0)

__global__ void __launch_bounds__(512) lstm_gemm8(
    const u16* __restrict__ Abf, const u16* __restrict__ Wbf,
    const float* __restrict__ bix, const float* __restrict__ bfx,
    const float* __restrict__ bcx, const float* __restrict__ box_,
    const float* __restrict__ bih, const float* __restrict__ bfh,
    const float* __restrict__ bch, const float* __restrict__ boh,
    const float* __restrict__ cprev, float* __restrict__ out) {
  __shared__ alignas(16) u16 sA[2 * 16384];   // 64 KB: [dbuf][256 rows][64 k]
  __shared__ alignas(16) u16 sB[2 * 16384];   // 64 KB

  const u32 tid = threadIdx.x;
  const u32 lane = tid & 63u, wid = tid >> 6;
  const u32 wr = wid >> 2, wc = wid & 3u;
  const u32 l15 = lane & 15u, l4 = lane >> 4;

  const u32 bid = blockIdx.x;
  const u32 sid = (bid & 7u) * 128u + (bid >> 3);   // bijective: 1024 % 8 == 0
  const u32 bm = sid >> 4, bn = sid & 15u;

  // staging source pointers: chunk = (wid*2+j)*64 + lane within a 128-row half
  const u16* gA[2][2];
  const u16* gB[2][2];
  #pragma unroll
  for (int h = 0; h < 2; ++h)
    #pragma unroll
    for (int j = 0; j < 2; ++j) {
      u32 chunk = (wid * 2u + (u32)j) * 64u + lane;
      u32 row = chunk >> 3, c = chunk & 7u;
      u32 col16 = c ^ (row & 7u);                   // inverse-swizzled source
      gA[h][j] = Abf + (size_t)(bm * 256u + (u32)h * 128u + row) * KTOT + col16 * 8u;
      u32 fr = (u32)h * 128u + row;
      u32 fi = fr >> 4;
      u32 Wrow = (fi & 3u) * 1024u + bn * 64u + (fi >> 2) * 16u + (fr & 15u);
      gB[h][j] = Wbf + (size_t)Wrow * KTOT + col16 * 8u;
    }

#define STAGE_A(ktile, dbuf) do { \
    gl_lds16(gA[0][0] + (ktile) * 64, sA + (dbuf) * 16384u + (wid * 2u + 0u) * 512u); \
    gl_lds16(gA[0][1] + (ktile) * 64, sA + (dbuf) * 16384u + (wid * 2u + 1u) * 512u); \
    gl_lds16(gA[1][0] + (ktile) * 64, sA + (dbuf) * 16384u + 8192u + (wid * 2u + 0u) * 512u); \
    gl_lds16(gA[1][1] + (ktile) * 64, sA + (dbuf) * 16384u + 8192u + (wid * 2u + 1u) * 512u); } while (0)
#define STAGE_B_H(ktile, dbuf, hh) do { \
    gl_lds16(gB[hh][0] + (ktile) * 64, sB + (dbuf) * 16384u + (hh) * 8192u + (wid * 2u + 0u) * 512u); \
    gl_lds16(gB[hh][1] + (ktile) * 64, sB + (dbuf) * 16384u + (hh) * 8192u + (wid * 2u + 1u) * 512u); } while (0)

  const char* cA = (const char*)sA;
  const char* cB = (const char*)sB;
  const u32 swzk[2] = { ((0u * 4u + l4) ^ (l15 & 7u)) << 4, ((1u * 4u + l4) ^ (l15 & 7u)) << 4 };

  f32x4 acc[8][4];
  #pragma unroll
  for (int mf = 0; mf < 8; ++mf)
    #pragma unroll
    for (int gf = 0; gf < 4; ++gf)
      acc[mf][gf] = (f32x4){0.f, 0.f, 0.f, 0.f};

  // prologue: kt0 A+B, kt1 A. vmcnt(4) leaves kt1.A in flight.
  STAGE_A(0, 0);
  STAGE_B_H(0, 0, 0); STAGE_B_H(0, 0, 1);
  STAGE_A(1, 1);
  SBAR();
  asm volatile("s_waitcnt vmcnt(4)" ::: "memory");
  __builtin_amdgcn_s_barrier();
  SBAR();

  #pragma unroll 2
  for (int kt = 0; kt < 32; ++kt) {
    const u32 d = (u32)kt & 1u, dn = d ^ 1u;
    const u32 dA = d * 32768u, dB = d * 32768u;
    bf16x8 a03[4][2], a47[4][2], b01[2][2], b23[2][2];

    // ---- phase 0: read A(mf0-3)+B(gf0-1); stage kt+1.B half0; MFMA mf0-3 x gf0-1
    #pragma unroll
    for (int mf = 0; mf < 4; ++mf) {
      u32 rb = dA + (wr * 128u + (u32)mf * 16u + l15) * 128u;
      a03[mf][0] = *(const bf16x8*)(cA + rb + swzk[0]);
      a03[mf][1] = *(const bf16x8*)(cA + rb + swzk[1]);
    }
    #pragma unroll
    for (int gf = 0; gf < 2; ++gf) {
      u32 rb = dB + (wc * 64u + (u32)gf * 16u + l15) * 128u;
      b01[gf][0] = *(const bf16x8*)(cB + rb + swzk[0]);
      b01[gf][1] = *(const bf16x8*)(cB + rb + swzk[1]);
    }
    if (kt < 31) STAGE_B_H(kt + 1, dn, 0);
    SBAR();
    __builtin_amdgcn_s_barrier();
    asm volatile("s_waitcnt lgkmcnt(0)" ::: "memory");
    SBAR();
    __builtin_amdgcn_s_setprio(1);
    #pragma unroll
    for (int ks = 0; ks < 2; ++ks)
      #pragma unroll
      for (int gf = 0; gf < 2; ++gf)
        #pragma unroll
        for (int mf = 0; mf < 4; ++mf)
          acc[mf][gf] = __builtin_amdgcn_mfma_f32_16x16x32_bf16(a03[mf][ks], b01[gf][ks], acc[mf][gf], 0, 0, 0);
    __builtin_amdgcn_s_setprio(0);
    SBAR();
    __builtin_amdgcn_s_barrier();
    SBAR();

    // ---- phase 1: read B(gf2-3); stage kt+1.B half1; MFMA mf0-3 x gf2-3
    #pragma unroll
    for (int gf = 0; gf < 2; ++gf) {
      u32 rb = dB + (wc * 64u + (2u + (u32)gf) * 16u + l15) * 128u;
      b23[gf][0] = *(const bf16x8*)(cB + rb + swzk[0]);
      b23[gf][1] = *(const bf16x8*)(cB + rb + swzk[1]);
    }
    if (kt < 31) STAGE_B_H(kt + 1, dn, 1);
    SBAR();
    __builtin_amdgcn_s_barrier();
    asm volatile("s_waitcnt lgkmcnt(0)" ::: "memory");
    SBAR();
    __builtin_amdgcn_s_setprio(1);
    #pragma unroll
    for (int ks = 0; ks < 2; ++ks)
      #pragma unroll
      for (int gf = 0; gf < 2; ++gf)
        #pragma unroll
        for (int mf = 0; mf < 4; ++mf)
          acc[mf][2 + gf] = __builtin_amdgcn_mfma_f32_16x16x32_bf16(a03[mf][ks], b23[gf][ks], acc[mf][2 + gf], 0, 0, 0);
    __builtin_amdgcn_s_setprio(0);
    SBAR();
    __builtin_amdgcn_s_barrier();
    SBAR();

    // ---- phase 2: read A(mf4-7); MFMA mf4-7 x gf0-1
    #pragma unroll
    for (int mf = 0; mf < 4; ++mf) {
      u32 rb = dA + (wr * 128u + (4u + (u32)mf) * 16u + l15) * 128u;
      a47[mf][0] = *(const bf16x8*)(cA + rb + swzk[0]);
      a47[mf][1] = *(const bf16x8*)(cA + rb + swzk[1]);
    }
    SBAR();
    __builtin_amdgcn_s_barrier();
    asm volatile("s_waitcnt lgkmcnt(0)" ::: "memory");
    SBAR();
    __builtin_amdgcn_s_setprio(1);
    #pragma unroll
    for (int ks = 0; ks < 2; ++ks)
      #pragma unroll
      for (int gf = 0; gf < 2; ++gf)
        #pragma unroll
        for (int mf = 0; mf < 4; ++mf)
          acc[4 + mf][gf] = __builtin_amdgcn_mfma_f32_16x16x32_bf16(a47[mf][ks], b01[gf][ks], acc[4 + mf][gf], 0, 0, 0);
    __builtin_amdgcn_s_setprio(0);
    SBAR();
    __builtin_amdgcn_s_barrier();
    SBAR();

    // ---- phase 3: stage kt+2.A (into buf d, reads done at p2); counted vmcnt(4); MFMA mf4-7 x gf2-3
    if (kt < 30) {
      STAGE_A(kt + 2, d);
      SBAR();
      asm volatile("s_waitcnt vmcnt(4)" ::: "memory");   // kt+1 fully landed; kt+2.A stays in flight
    } else if (kt == 30) {
      SBAR();
      asm volatile("s_waitcnt vmcnt(0)" ::: "memory");   // drain last B
    }
    SBAR();
    __builtin_amdgcn_s_barrier();
    SBAR();
    __builtin_amdgcn_s_setprio(1);
    #pragma unroll
    for (int ks = 0; ks < 2; ++ks)
      #pragma unroll
      for (int gf = 0; gf < 2; ++gf)
        #pragma unroll
        for (int mf = 0; mf < 4; ++mf)
          acc[4 + mf][2 + gf] = __builtin_amdgcn_mfma_f32_16x16x32_bf16(a47[mf][ks], b23[gf][ks], acc[4 + mf][2 + gf], 0, 0, 0);
    __builtin_amdgcn_s_setprio(0);
    SBAR();
    __builtin_amdgcn_s_barrier();
    SBAR();
  }

  // ---- epilogue ----
  const u32 col = bn * 64u + wc * 16u + l15;
  const float bi = bix[col] + bih[col];
  const float bff = bfx[col] + bfh[col];
  const float bc = bcx[col] + bch[col];
  const float bo = box_[col] + boh[col];
  #pragma unroll
  for (int mf = 0; mf < 8; ++mf) {
    u32 row0 = bm * 256u + wr * 128u + (u32)mf * 16u + l4 * 4u;
    #pragma unroll
    for (int r = 0; r < 4; ++r) {
      size_t idx = (size_t)(row0 + (u32)r) * 1024 + col;
      float iv = acc[mf][0][r] + bi;
      float fv = acc[mf][1][r] + bff;
      float gv = tanh_fast(acc[mf][2][r] + bc);
      float ov = acc[mf][3][r] + bo;
      float cp = cprev[idx];
      float cn = gv * iv + cp * fv;
      out[idx] = ov * tanh_fast(cn);
      out[(size_t)16777216 + idx] = cn;
    }
  }
#undef STAGE_A
#undef STAGE_B_H
}

// ---- fallback (ws too small): round-1 reg-staged kernel, known correct ----
__global__ void __launch_bounds__(256, 2) lstm_gemm_fb(
    const float* __restrict__ x, const float* __restrict__ h,
    const float* __restrict__ wix, const float* __restrict__ wfx,
    const float* __restrict__ wcx, const float* __restrict__ wox,
    const float* __restrict__ wih, const float* __restrict__ wfh,
    const float* __restrict__ wch, const float* __restrict__ woh,
    const float* __restrict__ bix, const float* __restrict__ bfx,
    const float* __restrict__ bcx, const float* __restrict__ box_,
    const float* __restrict__ bih, const float* __restrict__ bfh,
    const float* __restrict__ bch, const float* __restrict__ boh,
    const float* __restrict__ cprev, float* __restrict__ out) {
  __shared__ alignas(16) u16 sA[128 * 64];
  __shared__ alignas(16) u16 sB[4 * 64 * 64];
  const u32 tid = threadIdx.x;
  const u32 lane = tid & 63u;
  const u32 wid = tid >> 6;
  const u32 wr = wid >> 1, wc = wid & 1u;
  const u32 bidx = blockIdx.x;
  const u32 bm = bidx >> 4, bn = bidx & 15u;
  f32x4 acc[4][4][2];
  #pragma unroll
  for (int g = 0; g < 4; ++g)
    #pragma unroll
    for (int m = 0; m < 4; ++m)
      #pragma unroll
      for (int n = 0; n < 2; ++n)
        acc[g][m][n] = (f32x4){0.f, 0.f, 0.f, 0.f};
  const u32 l15 = lane & 15u, l4 = lane >> 4;
  for (int kt = 0; kt < KTOT / 64; ++kt) {
    const u32 k0 = (u32)kt * 64u;
    if (kt) __syncthreads();
    #pragma unroll
    for (int c = 0; c < 4; ++c) {
      u32 chunk = tid + (u32)c * 256u;
      u32 row = chunk >> 3;
      u32 cp = (chunk & 7u) * 8u;
      u32 gk = k0 + cp;
      const float* src = (gk < 1024u) ? (x + (size_t)(bm * 128u + row) * 1024 + gk)
                                      : (h + (size_t)(bm * 128u + row) * 1024 + (gk - 1024u));
      float4 lo = *(const float4*)src;
      float4 hi = *(const float4*)(src + 4);
      u32 dst = row * 128u + ((cp * 2u) ^ ((row & 7u) << 4));
      *(bf16x8*)((char*)sA + dst) = pack8(lo, hi);
    }
    #pragma unroll
    for (int g = 0; g < 4; ++g) {
      const float* Wxg = (g == 0) ? wix : (g == 1) ? wfx : (g == 2) ? wcx : wox;
      const float* Whg = (g == 0) ? wih : (g == 1) ? wfh : (g == 2) ? wch : woh;
      #pragma unroll
      for (int cc = 0; cc < 2; ++cc) {
        u32 c3 = tid + (u32)cc * 256u;
        u32 row = c3 >> 3;
        u32 cp = (c3 & 7u) * 8u;
        u32 gk = k0 + cp;
        const float* src = (gk < 1024u) ? (Wxg + (size_t)(bn * 64u + row) * 1024 + gk)
                                        : (Whg + (size_t)(bn * 64u + row) * 1024 + (gk - 1024u));
        float4 lo = *(const float4*)src;
        float4 hi = *(const float4*)(src + 4);
        u32 dst = (u32)g * 8192u + row * 128u + ((cp * 2u) ^ ((row & 7u) << 4));
        *(bf16x8*)((char*)sB + dst) = pack8(lo, hi);
      }
    }
    __syncthreads();
    #pragma unroll
    for (int s = 0; s < 2; ++s) {
      bf16x8 af[4];
      #pragma unroll
      for (int m = 0; m < 4; ++m) {
        u32 mrow = wr * 64u + (u32)m * 16u + l15;
        u32 off = mrow * 128u + (((u32)s * 64u + l4 * 16u) ^ ((mrow & 7u) << 4));
        af[m] = *(const bf16x8*)((const char*)sA + off);
      }
      #pragma unroll
      for (int g = 0; g < 4; ++g) {
        #pragma unroll
        for (int nf = 0; nf < 2; ++nf) {
          u32 nrow = wc * 32u + (u32)nf * 16u + l15;
          u32 off = (u32)g * 8192u + nrow * 128u +
                    (((u32)s * 64u + l4 * 16u) ^ ((nrow & 7u) << 4));
          bf16x8 bfr = *(const bf16x8*)((const char*)sB + off);
          #pragma unroll
          for (int m = 0; m < 4; ++m)
            acc[g][m][nf] = __builtin_amdgcn_mfma_f32_16x16x32_bf16(af[m], bfr, acc[g][m][nf], 0, 0, 0);
        }
      }
    }
  }
  #pragma unroll
  for (int nf = 0; nf < 2; ++nf) {
    u32 col = bn * 64u + wc * 32u + (u32)nf * 16u + l15;
    float bi = bix[col] + bih[col];
    float bff = bfx[col] + bfh[col];
    float bc = bcx[col] + bch[col];
    float bo = box_[col] + boh[col];
    #pragma unroll
    for (int m = 0; m < 4; ++m) {
      u32 row0 = bm * 128u + wr * 64u + (u32)m * 16u + l4 * 4u;
      #pragma unroll
      for (int r = 0; r < 4; ++r) {
        size_t idx = (size_t)(row0 + (u32)r) * 1024 + col;
        float iv = acc[0][m][nf][r] + bi;
        float fv = acc[1][m][nf][r] + bff;
        float gv = tanh_fast(acc[2][m][nf][r] + bc);
        float ov = acc[3][m][nf][r] + bo;
        float cp = cprev[idx];
        float cn = gv * iv + cp * fv;
        out[idx] = ov * tanh_fast(cn);
        out[(size_t)16777216 + idx] = cn;
      }
    }
  }
}

extern "C" void kernel_launch(void* const* d_in, const int* in_sizes, int n_in,
                              void* d_out, int out_size, void* d_ws, size_t ws_size,
                              hipStream_t stream) {
  const float* x = (const float*)d_in[0];
  const float* h = (const float*)d_in[1];
  const float* cprev = (const float*)d_in[2];
  const float* wix = (const float*)d_in[3];  const float* bix = (const float*)d_in[4];
  const float* wfx = (const float*)d_in[5];  const float* bfx = (const float*)d_in[6];
  const float* wcx = (const float*)d_in[7];  const float* bcx = (const float*)d_in[8];
  const float* wox = (const float*)d_in[9];  const float* box_ = (const float*)d_in[10];
  const float* wih = (const float*)d_in[11]; const float* bih = (const float*)d_in[12];
  const float* wfh = (const float*)d_in[13]; const float* bfh = (const float*)d_in[14];
  const float* wch = (const float*)d_in[15]; const float* bch = (const float*)d_in[16];
  const float* woh = (const float*)d_in[17]; const float* boh = (const float*)d_in[18];
  float* out = (float*)d_out;

  const size_t needA = (size_t)MROWS * KTOT * 2;
  const size_t needW = (size_t)4 * NCOLS * KTOT * 2;

  if (ws_size >= needA + needW) {
    u16* Abf = (u16*)d_ws;
    u16* Wbf = (u16*)((char*)d_ws + needA);
    convA<<<dim3(4096), dim3(256), 0, stream>>>(x, h, Abf);
    convW<<<dim3(1024), dim3(256), 0, stream>>>(wix, wfx, wcx, wox, wih, wfh, wch, woh, Wbf);
    lstm_gemm8<<<dim3(1024), dim3(512), 0, stream>>>(
        Abf, Wbf, bix, bfx, bcx, box_, bih, bfh, bch, boh, cprev, out);
  } else {
    lstm_gemm_fb<<<dim3(2048), dim3(256), 0, stream>>>(
        x, h, wix, wfx, wcx, wox, wih, wfh, wch, woh,
        bix, bfx, bcx, box_, bih, bfh, bch, boh, cprev, out);
  }
}

// Round 3
// 336.958 us; speedup vs baseline: 1.0159x; 1.0159x over previous
//
#include <hip/hip_runtime.h>
#include <hip/hip_bf16.h>

// LSTM cell: B=16384, D=H=1024. out = (h_next, c_next) fp32, each 16384x1024.
// bf16-MFMA fused 4-gate GEMM, 4-phase counted-vmcnt schedule (T1+T2+T3+T4+T5),
// 2-K-tile-deep prefetch (vmcnt(8), never 0 in steady state).

#define MROWS 16384
#define NCOLS 1024
#define KTOT  2048

typedef __attribute__((ext_vector_type(8))) short bf16x8;
typedef __attribute__((ext_vector_type(4))) float f32x4;
typedef unsigned int u32;
typedef unsigned short u16;

__device__ __forceinline__ u16 f2bf(float f) {
  union { float f; u32 u; } v; v.f = f;
  u32 r = v.u + 0x7fffu + ((v.u >> 16) & 1u);   // RNE truncate f32->bf16
  return (u16)(r >> 16);
}

__device__ __forceinline__ bf16x8 pack8(float4 lo, float4 hi) {
  bf16x8 v;
  v[0] = (short)f2bf(lo.x); v[1] = (short)f2bf(lo.y);
  v[2] = (short)f2bf(lo.z); v[3] = (short)f2bf(lo.w);
  v[4] = (short)f2bf(hi.x); v[5] = (short)f2bf(hi.y);
  v[6] = (short)f2bf(hi.z); v[7] = (short)f2bf(hi.w);
  return v;
}

__device__ __forceinline__ float tanh_fast(float x) {
  float e = __expf(2.0f * x);
  return 1.0f - 2.0f / (e + 1.0f);
}

typedef __attribute__((address_space(1))) const u32 gas_u32;
typedef __attribute__((address_space(3))) u32 las_u32;

__device__ __forceinline__ void gl_lds16(const void* g, void* l) {
  __builtin_amdgcn_global_load_lds((gas_u32*)g, (las_u32*)l, 16, 0, 0);
}

// ---- conversion kernels ----
__global__ void __launch_bounds__(256) convA(const float* __restrict__ x,
                                             const float* __restrict__ h,
                                             u16* __restrict__ A) {
  u32 t = blockIdx.x * 256u + threadIdx.x;
  #pragma unroll
  for (int i = 0; i < 4; ++i) {
    u32 chunk = t + (u32)i * 1048576u;
    u32 row = chunk >> 8;
    u32 cpos = (chunk & 255u) * 8u;
    const float* src = (cpos < 1024u) ? (x + (size_t)row * 1024 + cpos)
                                      : (h + (size_t)row * 1024 + (cpos - 1024u));
    float4 lo = *(const float4*)src;
    float4 hi = *(const float4*)(src + 4);
    *(bf16x8*)(A + (size_t)chunk * 8) = pack8(lo, hi);
  }
}

__global__ void __launch_bounds__(256) convW(const float* __restrict__ wix, const float* __restrict__ wfx,
                                             const float* __restrict__ wcx, const float* __restrict__ wox,
                                             const float* __restrict__ wih, const float* __restrict__ wfh,
                                             const float* __restrict__ wch, const float* __restrict__ woh,
                                             u16* __restrict__ W) {
  u32 t = blockIdx.x * 256u + threadIdx.x;
  const float* WX[4] = {wix, wfx, wcx, wox};
  const float* WH[4] = {wih, wfh, wch, woh};
  #pragma unroll
  for (int g = 0; g < 4; ++g) {
    u32 c3 = t;
    u32 n = c3 >> 8;
    u32 cpos = (c3 & 255u) * 8u;
    const float* src = (cpos < 1024u) ? (WX[g] + (size_t)n * 1024 + cpos)
                                      : (WH[g] + (size_t)n * 1024 + (cpos - 1024u));
    float4 lo = *(const float4*)src;
    float4 hi = *(const float4*)(src + 4);
    *(bf16x8*)(W + (size_t)g * 2097152 + (size_t)c3 * 8) = pack8(lo, hi);
  }
}

// ---- 4-phase fused GEMM ----
// Block: 512 thr = 8 waves (wr 0-1 M-halves x wc 0-3 N-colblocks).
// Tile: 256(M) x [4 gates x 64](N), BK=64, 32 K-tiles.
// B fused rows: fr in [0,256): fi=fr>>4, colblock=fi>>2(==wc), gate=fi&3, col=fr&15.
// LDS: sA[2 dbuf][256][64], sB same = 128 KB. XOR swizzle chunk^=(row&7).
// Schedule per kt: ph0 {rd a03,b01 | bar | MFMA} ph1 {rd b23 | bar | MFMA}
//                  ph2 {stage B(kt+2)->d; rd a47 | bar | MFMA}
//                  ph3 {stage A(kt+2)->d; vmcnt(8) | bar | MFMA}
#define SBAR() __builtin_amdgcn_sched_barrier(0)

__global__ void __launch_bounds__(512) lstm_gemm8(
    const u16* __restrict__ Abf, const u16* __restrict__ Wbf,
    const float* __restrict__ bix, const float* __restrict__ bfx,
    const float* __restrict__ bcx, const float* __restrict__ box_,
    const float* __restrict__ bih, const float* __restrict__ bfh,
    const float* __restrict__ bch, const float* __restrict__ boh,
    const float* __restrict__ cprev, float* __restrict__ out) {
  __shared__ alignas(16) u16 sA[2 * 16384];   // 64 KB: [dbuf][256 rows][64 k]
  __shared__ alignas(16) u16 sB[2 * 16384];   // 64 KB

  const u32 tid = threadIdx.x;
  const u32 lane = tid & 63u, wid = tid >> 6;
  const u32 wr = wid >> 2, wc = wid & 3u;
  const u32 l15 = lane & 15u, l4 = lane >> 4;

  const u32 bid = blockIdx.x;
  const u32 sid = (bid & 7u) * 128u + (bid >> 3);   // bijective: 1024 % 8 == 0
  const u32 bm = sid >> 4, bn = sid & 15u;

  // staging source pointers: chunk = (wid*2+j)*64 + lane within a 128-row half
  const u16* gA[2][2];
  const u16* gB[2][2];
  #pragma unroll
  for (int h = 0; h < 2; ++h)
    #pragma unroll
    for (int j = 0; j < 2; ++j) {
      u32 chunk = (wid * 2u + (u32)j) * 64u + lane;
      u32 row = chunk >> 3, c = chunk & 7u;
      u32 col16 = c ^ (row & 7u);                   // inverse-swizzled source
      gA[h][j] = Abf + (size_t)(bm * 256u + (u32)h * 128u + row) * KTOT + col16 * 8u;
      u32 fr = (u32)h * 128u + row;
      u32 fi = fr >> 4;
      u32 Wrow = (fi & 3u) * 1024u + bn * 64u + (fi >> 2) * 16u + (fr & 15u);
      gB[h][j] = Wbf + (size_t)Wrow * KTOT + col16 * 8u;
    }

#define STAGE_A(ktile, dbuf) do { \
    gl_lds16(gA[0][0] + (ktile) * 64, sA + (dbuf) * 16384u + (wid * 2u + 0u) * 512u); \
    gl_lds16(gA[0][1] + (ktile) * 64, sA + (dbuf) * 16384u + (wid * 2u + 1u) * 512u); \
    gl_lds16(gA[1][0] + (ktile) * 64, sA + (dbuf) * 16384u + 8192u + (wid * 2u + 0u) * 512u); \
    gl_lds16(gA[1][1] + (ktile) * 64, sA + (dbuf) * 16384u + 8192u + (wid * 2u + 1u) * 512u); } while (0)
#define STAGE_B(ktile, dbuf) do { \
    gl_lds16(gB[0][0] + (ktile) * 64, sB + (dbuf) * 16384u + (wid * 2u + 0u) * 512u); \
    gl_lds16(gB[0][1] + (ktile) * 64, sB + (dbuf) * 16384u + (wid * 2u + 1u) * 512u); \
    gl_lds16(gB[1][0] + (ktile) * 64, sB + (dbuf) * 16384u + 8192u + (wid * 2u + 0u) * 512u); \
    gl_lds16(gB[1][1] + (ktile) * 64, sB + (dbuf) * 16384u + 8192u + (wid * 2u + 1u) * 512u); } while (0)

  const char* cA = (const char*)sA;
  const char* cB = (const char*)sB;
  const u32 swzk[2] = { ((0u * 4u + l4) ^ (l15 & 7u)) << 4, ((1u * 4u + l4) ^ (l15 & 7u)) << 4 };

  f32x4 acc[8][4];
  #pragma unroll
  for (int mf = 0; mf < 8; ++mf)
    #pragma unroll
    for (int gf = 0; gf < 4; ++gf)
      acc[mf][gf] = (f32x4){0.f, 0.f, 0.f, 0.f};

  // prologue: kt0 -> buf0 (8 loads), kt1 -> buf1 (8 loads); vmcnt(8) = buf0 landed.
  STAGE_B(0, 0); STAGE_A(0, 0);
  STAGE_B(1, 1); STAGE_A(1, 1);
  asm volatile("s_waitcnt vmcnt(8)" ::: "memory");
  __builtin_amdgcn_s_barrier();

  #pragma unroll 2
  for (int kt = 0; kt < 32; ++kt) {
    const u32 d = (u32)kt & 1u;
    const u32 dO = d * 32768u;                      // byte offset of current buffer
    bf16x8 a03[4][2], a47[4][2], b01[2][2], b23[2][2];

    // ---- phase 0: read a03 + b01; MFMA a03 x b01
    #pragma unroll
    for (int mf = 0; mf < 4; ++mf) {
      u32 rb = dO + (wr * 128u + (u32)mf * 16u + l15) * 128u;
      a03[mf][0] = *(const bf16x8*)(cA + rb + swzk[0]);
      a03[mf][1] = *(const bf16x8*)(cA + rb + swzk[1]);
    }
    #pragma unroll
    for (int gf = 0; gf < 2; ++gf) {
      u32 rb = dO + (wc * 64u + (u32)gf * 16u + l15) * 128u;
      b01[gf][0] = *(const bf16x8*)(cB + rb + swzk[0]);
      b01[gf][1] = *(const bf16x8*)(cB + rb + swzk[1]);
    }
    __builtin_amdgcn_s_barrier();
    asm volatile("s_waitcnt lgkmcnt(0)" ::: "memory");
    SBAR();
    __builtin_amdgcn_s_setprio(1);
    #pragma unroll
    for (int ks = 0; ks < 2; ++ks)
      #pragma unroll
      for (int gf = 0; gf < 2; ++gf)
        #pragma unroll
        for (int mf = 0; mf < 4; ++mf)
          acc[mf][gf] = __builtin_amdgcn_mfma_f32_16x16x32_bf16(a03[mf][ks], b01[gf][ks], acc[mf][gf], 0, 0, 0);
    __builtin_amdgcn_s_setprio(0);
    __builtin_amdgcn_s_barrier();

    // ---- phase 1: read b23; MFMA a03 x b23   (B(kt) region free after this phase)
    #pragma unroll
    for (int gf = 0; gf < 2; ++gf) {
      u32 rb = dO + (wc * 64u + (2u + (u32)gf) * 16u + l15) * 128u;
      b23[gf][0] = *(const bf16x8*)(cB + rb + swzk[0]);
      b23[gf][1] = *(const bf16x8*)(cB + rb + swzk[1]);
    }
    __builtin_amdgcn_s_barrier();
    asm volatile("s_waitcnt lgkmcnt(0)" ::: "memory");
    SBAR();
    __builtin_amdgcn_s_setprio(1);
    #pragma unroll
    for (int ks = 0; ks < 2; ++ks)
      #pragma unroll
      for (int gf = 0; gf < 2; ++gf)
        #pragma unroll
        for (int mf = 0; mf < 4; ++mf)
          acc[mf][2 + gf] = __builtin_amdgcn_mfma_f32_16x16x32_bf16(a03[mf][ks], b23[gf][ks], acc[mf][2 + gf], 0, 0, 0);
    __builtin_amdgcn_s_setprio(0);
    __builtin_amdgcn_s_barrier();

    // ---- phase 2: stage B(kt+2) -> buf d (region just freed); read a47; MFMA a47 x b01
    if (kt < 30) STAGE_B(kt + 2, d);
    #pragma unroll
    for (int mf = 0; mf < 4; ++mf) {
      u32 rb = dO + (wr * 128u + (4u + (u32)mf) * 16u + l15) * 128u;
      a47[mf][0] = *(const bf16x8*)(cA + rb + swzk[0]);
      a47[mf][1] = *(const bf16x8*)(cA + rb + swzk[1]);
    }
    __builtin_amdgcn_s_barrier();
    asm volatile("s_waitcnt lgkmcnt(0)" ::: "memory");
    SBAR();
    __builtin_amdgcn_s_setprio(1);
    #pragma unroll
    for (int ks = 0; ks < 2; ++ks)
      #pragma unroll
      for (int gf = 0; gf < 2; ++gf)
        #pragma unroll
        for (int mf = 0; mf < 4; ++mf)
          acc[4 + mf][gf] = __builtin_amdgcn_mfma_f32_16x16x32_bf16(a47[mf][ks], b01[gf][ks], acc[4 + mf][gf], 0, 0, 0);
    __builtin_amdgcn_s_setprio(0);
    __builtin_amdgcn_s_barrier();

    // ---- phase 3: stage A(kt+2) -> buf d (A region free after ph2); counted vmcnt(8):
    //      retires B(kt+1),A(kt+1) (issued a full K-tile ago); leaves B(kt+2),A(kt+2) in flight.
    if (kt < 30) {
      STAGE_A(kt + 2, d);
      asm volatile("s_waitcnt vmcnt(8)" ::: "memory");
    } else if (kt == 30) {
      asm volatile("s_waitcnt vmcnt(0)" ::: "memory");
    }
    __builtin_amdgcn_s_barrier();
    __builtin_amdgcn_s_setprio(1);
    #pragma unroll
    for (int ks = 0; ks < 2; ++ks)
      #pragma unroll
      for (int gf = 0; gf < 2; ++gf)
        #pragma unroll
        for (int mf = 0; mf < 4; ++mf)
          acc[4 + mf][2 + gf] = __builtin_amdgcn_mfma_f32_16x16x32_bf16(a47[mf][ks], b23[gf][ks], acc[4 + mf][2 + gf], 0, 0, 0);
    __builtin_amdgcn_s_setprio(0);
    __builtin_amdgcn_s_barrier();
  }

  // ---- epilogue ----
  const u32 col = bn * 64u + wc * 16u + l15;
  const float bi = bix[col] + bih[col];
  const float bff = bfx[col] + bfh[col];
  const float bc = bcx[col] + bch[col];
  const float bo = box_[col] + boh[col];
  #pragma unroll
  for (int mf = 0; mf < 8; ++mf) {
    u32 row0 = bm * 256u + wr * 128u + (u32)mf * 16u + l4 * 4u;
    #pragma unroll
    for (int r = 0; r < 4; ++r) {
      size_t idx = (size_t)(row0 + (u32)r) * 1024 + col;
      float iv = acc[mf][0][r] + bi;
      float fv = acc[mf][1][r] + bff;
      float gv = tanh_fast(acc[mf][2][r] + bc);
      float ov = acc[mf][3][r] + bo;
      float cp = cprev[idx];
      float cn = gv * iv + cp * fv;
      out[idx] = ov * tanh_fast(cn);
      out[(size_t)16777216 + idx] = cn;
    }
  }
#undef STAGE_A
#undef STAGE_B
}

// ---- fallback (ws too small): round-1 reg-staged kernel, known correct ----
__global__ void __launch_bounds__(256, 2) lstm_gemm_fb(
    const float* __restrict__ x, const float* __restrict__ h,
    const float* __restrict__ wix, const float* __restrict__ wfx,
    const float* __restrict__ wcx, const float* __restrict__ wox,
    const float* __restrict__ wih, const float* __restrict__ wfh,
    const float* __restrict__ wch, const float* __restrict__ woh,
    const float* __restrict__ bix, const float* __restrict__ bfx,
    const float* __restrict__ bcx, const float* __restrict__ box_,
    const float* __restrict__ bih, const float* __restrict__ bfh,
    const float* __restrict__ bch, const float* __restrict__ boh,
    const float* __restrict__ cprev, float* __restrict__ out) {
  __shared__ alignas(16) u16 sA[128 * 64];
  __shared__ alignas(16) u16 sB[4 * 64 * 64];
  const u32 tid = threadIdx.x;
  const u32 lane = tid & 63u;
  const u32 wid = tid >> 6;
  const u32 wr = wid >> 1, wc = wid & 1u;
  const u32 bidx = blockIdx.x;
  const u32 bm = bidx >> 4, bn = bidx & 15u;
  f32x4 acc[4][4][2];
  #pragma unroll
  for (int g = 0; g < 4; ++g)
    #pragma unroll
    for (int m = 0; m < 4; ++m)
      #pragma unroll
      for (int n = 0; n < 2; ++n)
        acc[g][m][n] = (f32x4){0.f, 0.f, 0.f, 0.f};
  const u32 l15 = lane & 15u, l4 = lane >> 4;
  for (int kt = 0; kt < KTOT / 64; ++kt) {
    const u32 k0 = (u32)kt * 64u;
    if (kt) __syncthreads();
    #pragma unroll
    for (int c = 0; c < 4; ++c) {
      u32 chunk = tid + (u32)c * 256u;
      u32 row = chunk >> 3;
      u32 cp = (chunk & 7u) * 8u;
      u32 gk = k0 + cp;
      const float* src = (gk < 1024u) ? (x + (size_t)(bm * 128u + row) * 1024 + gk)
                                      : (h + (size_t)(bm * 128u + row) * 1024 + (gk - 1024u));
      float4 lo = *(const float4*)src;
      float4 hi = *(const float4*)(src + 4);
      u32 dst = row * 128u + ((cp * 2u) ^ ((row & 7u) << 4));
      *(bf16x8*)((char*)sA + dst) = pack8(lo, hi);
    }
    #pragma unroll
    for (int g = 0; g < 4; ++g) {
      const float* Wxg = (g == 0) ? wix : (g == 1) ? wfx : (g == 2) ? wcx : wox;
      const float* Whg = (g == 0) ? wih : (g == 1) ? wfh : (g == 2) ? wch : woh;
      #pragma unroll
      for (int cc = 0; cc < 2; ++cc) {
        u32 c3 = tid + (u32)cc * 256u;
        u32 row = c3 >> 3;
        u32 cp = (c3 & 7u) * 8u;
        u32 gk = k0 + cp;
        const float* src = (gk < 1024u) ? (Wxg + (size_t)(bn * 64u + row) * 1024 + gk)
                                        : (Whg + (size_t)(bn * 64u + row) * 1024 + (gk - 1024u));
        float4 lo = *(const float4*)src;
        float4 hi = *(const float4*)(src + 4);
        u32 dst = (u32)g * 8192u + row * 128u + ((cp * 2u) ^ ((row & 7u) << 4));
        *(bf16x8*)((char*)sB + dst) = pack8(lo, hi);
      }
    }
    __syncthreads();
    #pragma unroll
    for (int s = 0; s < 2; ++s) {
      bf16x8 af[4];
      #pragma unroll
      for (int m = 0; m < 4; ++m) {
        u32 mrow = wr * 64u + (u32)m * 16u + l15;
        u32 off = mrow * 128u + (((u32)s * 64u + l4 * 16u) ^ ((mrow & 7u) << 4));
        af[m] = *(const bf16x8*)((const char*)sA + off);
      }
      #pragma unroll
      for (int g = 0; g < 4; ++g) {
        #pragma unroll
        for (int nf = 0; nf < 2; ++nf) {
          u32 nrow = wc * 32u + (u32)nf * 16u + l15;
          u32 off = (u32)g * 8192u + nrow * 128u +
                    (((u32)s * 64u + l4 * 16u) ^ ((nrow & 7u) << 4));
          bf16x8 bfr = *(const bf16x8*)((const char*)sB + off);
          #pragma unroll
          for (int m = 0; m < 4; ++m)
            acc[g][m][nf] = __builtin_amdgcn_mfma_f32_16x16x32_bf16(af[m], bfr, acc[g][m][nf], 0, 0, 0);
        }
      }
    }
  }
  #pragma unroll
  for (int nf = 0; nf < 2; ++nf) {
    u32 col = bn * 64u + wc * 32u + (u32)nf * 16u + l15;
    float bi = bix[col] + bih[col];
    float bff = bfx[col] + bfh[col];
    float bc = bcx[col] + bch[col];
    float bo = box_[col] + boh[col];
    #pragma unroll
    for (int m = 0; m < 4; ++m) {
      u32 row0 = bm * 128u + wr * 64u + (u32)m * 16u + l4 * 4u;
      #pragma unroll
      for (int r = 0; r < 4; ++r) {
        size_t idx = (size_t)(row0 + (u32)r) * 1024 + col;
        float iv = acc[0][m][nf][r] + bi;
        float fv = acc[1][m][nf][r] + bff;
        float gv = tanh_fast(acc[2][m][nf][r] + bc);
        float ov = acc[3][m][nf][r] + bo;
        float cp = cprev[idx];
        float cn = gv * iv + cp * fv;
        out[idx] = ov * tanh_fast(cn);
        out[(size_t)16777216 + idx] = cn;
      }
    }
  }
}

extern "C" void kernel_launch(void* const* d_in, const int* in_sizes, int n_in,
                              void* d_out, int out_size, void* d_ws, size_t ws_size,
                              hipStream_t stream) {
  const float* x = (const float*)d_in[0];
  const float* h = (const float*)d_in[1];
  const float* cprev = (const float*)d_in[2];
  const float* wix = (const float*)d_in[3];  const float* bix = (const float*)d_in[4];
  const float* wfx = (const float*)d_in[5];  const float* bfx = (const float*)d_in[6];
  const float* wcx = (const float*)d_in[7];  const float* bcx = (const float*)d_in[8];
  const float* wox = (const float*)d_in[9];  const float* box_ = (const float*)d_in[10];
  const float* wih = (const float*)d_in[11]; const float* bih = (const float*)d_in[12];
  const float* wfh = (const float*)d_in[13]; const float* bfh = (const float*)d_in[14];
  const float* wch = (const float*)d_in[15]; const float* bch = (const float*)d_in[16];
  const float* woh = (const float*)d_in[17]; const float* boh = (const float*)d_in[18];
  float* out = (float*)d_out;

  const size_t needA = (size_t)MROWS * KTOT * 2;
  const size_t needW = (size_t)4 * NCOLS * KTOT * 2;

  if (ws_size >= needA + needW) {
    u16* Abf = (u16*)d_ws;
    u16* Wbf = (u16*)((char*)d_ws + needA);
    convA<<<dim3(4096), dim3(256), 0, stream>>>(x, h, Abf);
    convW<<<dim3(1024), dim3(256), 0, stream>>>(wix, wfx, wcx, wox, wih, wfh, wch, woh, Wbf);
    lstm_gemm8<<<dim3(1024), dim3(512), 0, stream>>>(
        Abf, Wbf, bix, bfx, bcx, box_, bih, bfh, bch, boh, cprev, out);
  } else {
    lstm_gemm_fb<<<dim3(2048), dim3(256), 0, stream>>>(
        x, h, wix, wfx, wcx, wox, wih, wfh, wch, woh,
        bix, bfx, bcx, box_, bih, bfh, bch, boh, cprev, out);
  }
}